// Round 6
// baseline (117.539 us; speedup 1.0000x reference)
//
#include <hip/hip_runtime.h>
#include <stdint.h>

typedef __bf16 bf16x4 __attribute__((ext_vector_type(4)));
typedef __bf16 bf16x8 __attribute__((ext_vector_type(8)));
typedef float  f32x4  __attribute__((ext_vector_type(4)));

#define HID 1024
#define SEQ 2048
#define NB  8

// ---------------------------------------------------------------------------
// prep_w: convert 3x(64x1024) fp32 weight mats to bf16 (one-time, ~0.4 MB)
// ---------------------------------------------------------------------------
__global__ __launch_bounds__(256) void prep_w(
    const float* __restrict__ Wq, const float* __restrict__ Wk,
    const float* __restrict__ Wv, __bf16* __restrict__ Wb)
{
    const int i = blockIdx.x * 256 + threadIdx.x;     // 49152 float4s total
    const int mat = i >> 14;                          // / 16384
    const int j   = i & 16383;
    const float* src = ((mat == 0) ? Wq : (mat == 1) ? Wk : Wv) + j * 4;
    float4 f = *(const float4*)src;
    bf16x4 o = { (__bf16)f.x, (__bf16)f.y, (__bf16)f.z, (__bf16)f.w };
    *(bf16x4*)(Wb + (size_t)i * 4) = o;
}

// ---------------------------------------------------------------------------
// Projection v5: attn-style reg-staged pipeline (the structure that measures
// 4.7 TB/s in this workload). Epoch = 64 k-cols.
//   X: global -> VGPR (4x float4/thr, contiguous 256B per row-chunk)
//      -> bf16 -> ds_write into double-buffered 2x8KB tile.
//      Granule swizzle (8B): phys = u8 ^ ((row&7)<<1) — write & read agree.
//   W: direct L2 -> VGPR fragments, double-buffered (named Wa/Wb, static idx).
//   One __syncthreads per epoch; epoch e+1 loads issued right after it and
//   consumed a compute-phase later (compiler emits counted vmcnt).
// q gets *0.125 folded in. v stored transposed vT[b][d][s].
// ---------------------------------------------------------------------------
struct WFr { bf16x8 w[2][4]; };

__global__ __launch_bounds__(256) void proj_kernel(
    const float* __restrict__ Xq, const float* __restrict__ Xk, const float* __restrict__ Xv,
    const __bf16* __restrict__ Wb,
    const float* __restrict__ bq_, const float* __restrict__ bk_, const float* __restrict__ bv_,
    __bf16* __restrict__ qo, __bf16* __restrict__ ko, __bf16* __restrict__ vTo)
{
    const int mat = blockIdx.y;
    const float* X   = (mat == 0) ? Xq  : (mat == 1) ? Xk  : Xv;
    const __bf16* Wm = Wb + (size_t)mat * 64 * HID;
    const float* Bp  = (mat == 0) ? bq_ : (mat == 1) ? bk_ : bv_;

    const int row0 = blockIdx.x * 64;
    const int tid  = threadIdx.x;
    const int lane = tid & 63;
    const int wv   = tid >> 6;      // wave 0..3 -> rows wv*16..
    const int lr   = lane & 15;
    const int g    = lane >> 4;     // 0..3

    __shared__ __align__(16) __bf16 Xl[2][64 * 64];   // 2 x 8 KB

    f32x4 acc[4] = {};
    float4 xr[4];
    WFr Wa, Wb2;

    auto LOADX = [&](int e) {
        const int k0 = e * 64;
        #pragma unroll
        for (int i = 0; i < 4; ++i) {
            const int row = wv * 16 + 4 * i + (lane >> 4);
            xr[i] = *(const float4*)(X + (size_t)(row0 + row) * HID + k0 + (lane & 15) * 4);
        }
    };
    auto LOADW = [&](WFr& W, int e) {
        const int k0 = e * 64;
        #pragma unroll
        for (int s = 0; s < 2; ++s)
            #pragma unroll
            for (int ct = 0; ct < 4; ++ct)
                W.w[s][ct] = *(const bf16x8*)(Wm + (size_t)(ct * 16 + lr) * HID + k0 + 32 * s + 8 * g);
    };
    auto WRITEX = [&](int pb) {
        #pragma unroll
        for (int i = 0; i < 4; ++i) {
            const int row  = wv * 16 + 4 * i + (lane >> 4);
            const int phys = (lane & 15) ^ ((row & 7) << 1);
            bf16x4 v = { (__bf16)xr[i].x, (__bf16)xr[i].y, (__bf16)xr[i].z, (__bf16)xr[i].w };
            *(bf16x4*)&Xl[pb][row * 64 + phys * 4] = v;
        }
    };
    auto COMPUTE = [&](int pb, WFr& W) {
        const int arow = wv * 16 + lr;
        #pragma unroll
        for (int s = 0; s < 2; ++s) {
            const int phys = (8 * s + 2 * g) ^ ((lr & 7) << 1);
            bf16x8 af = *(const bf16x8*)&Xl[pb][arow * 64 + phys * 4];
            #pragma unroll
            for (int ct = 0; ct < 4; ++ct)
                acc[ct] = __builtin_amdgcn_mfma_f32_16x16x32_bf16(af, W.w[s][ct], acc[ct], 0, 0, 0);
        }
    };

    LOADX(0); LOADW(Wa, 0);

    #pragma unroll 1
    for (int e = 0; e < 16; e += 2) {
        // epoch e (buf 0, W = Wa)
        WRITEX(0);
        __syncthreads();
        LOADX(e + 1); LOADW(Wb2, e + 1);      // e+1 <= 15 always
        COMPUTE(0, Wa);
        // epoch e+1 (buf 1, W = Wb2)
        WRITEX(1);
        __syncthreads();
        if (e + 2 < 16) { LOADX(e + 2); LOADW(Wa, e + 2); }
        COMPUTE(1, Wb2);
    }

    const float scl = (mat == 0) ? 0.125f : 1.0f;
    float res[4][4];
    #pragma unroll
    for (int ct = 0; ct < 4; ++ct) {
        const float bval = Bp[ct * 16 + lr];
        #pragma unroll
        for (int rr = 0; rr < 4; ++rr) res[ct][rr] = (acc[ct][rr] + bval) * scl;
    }

    if (mat < 2) {
        __bf16* o = (mat == 0) ? qo : ko;
        // D-layout: row = 4g+rr, col = ct*16+lr
        #pragma unroll
        for (int ct = 0; ct < 4; ++ct)
            #pragma unroll
            for (int rr = 0; rr < 4; ++rr)
                o[(size_t)(row0 + wv * 16 + 4 * g + rr) * 64 + ct * 16 + lr] = (__bf16)res[ct][rr];
    } else {
        // transpose v tile via LDS (alias Xl: 16KB >= 9216B), write vT coalesced
        __bf16* Tl = &Xl[0][0];
        __syncthreads();
        #pragma unroll
        for (int ct = 0; ct < 4; ++ct)
            #pragma unroll
            for (int rr = 0; rr < 4; ++rr)
                Tl[(ct * 16 + lr) * 72 + wv * 16 + 4 * g + rr] = (__bf16)res[ct][rr];
        __syncthreads();
        const int d   = tid >> 2;
        const int sc_ = (tid & 3) * 16;
        const int b   = row0 >> 11;
        const int s0  = row0 & 2047;
        __bf16* dst = vTo + ((size_t)b * 64 + d) * SEQ + s0 + sc_;
        *(bf16x8*)dst       = *(const bf16x8*)&Tl[d * 72 + sc_];
        *(bf16x8*)(dst + 8) = *(const bf16x8*)&Tl[d * 72 + sc_ + 8];
    }
}

// ---------------------------------------------------------------------------
// Flash attention with additive bias + key mask (unchanged — passed, ~4.7 TB/s).
// 128 thr (2 waves x 16 q-rows = 32 q-rows/block), 512 blocks.
// Register-prefetch of next K/V tile + bias/mask one iteration ahead.
// ---------------------------------------------------------------------------
__global__ __launch_bounds__(128) void attn_kernel(
    const __bf16* __restrict__ qws, const __bf16* __restrict__ kws,
    const __bf16* __restrict__ vTws, const float* __restrict__ bias,
    const int* __restrict__ mask, float* __restrict__ out)
{
    const int bid = blockIdx.x;
    const int b   = bid & 7;            // batch -> XCD round-robin (K/V L2 locality)
    const int q0  = (bid >> 3) * 32;
    const int tid = threadIdx.x;
    const int lane = tid & 63;
    const int wv   = tid >> 6;          // 0..1
    const int lr   = lane & 15;
    const int g    = lane >> 4;

    __shared__ __align__(16) __bf16 Kl[64 * 72];
    __shared__ __align__(16) __bf16 Vl[64 * 72];

    const int qrow = q0 + wv * 16 + lr;

    bf16x8 qf[2];
    {
        const __bf16* qp = qws + (size_t)(b * SEQ + qrow) * 64;
        #pragma unroll
        for (int dt = 0; dt < 2; ++dt) {
            bf16x4 lo = *(const bf16x4*)(qp + dt * 32 + 4 * g);
            bf16x4 hi = *(const bf16x4*)(qp + dt * 32 + 16 + 4 * g);
            qf[dt] = __builtin_shufflevector(lo, hi, 0, 1, 2, 3, 4, 5, 6, 7);
        }
    }

    f32x4 O[4] = {};
    float m   = -3.0e38f;
    float ell = 0.0f;

    const float* brow = bias + (size_t)(b * SEQ + qrow) * SEQ;
    const int*   mrow = mask + b * SEQ;

    const int sr = tid >> 1;            // staging row 0..63
    const int sc = (tid & 1) * 32;      // 32 elems = 4x bf16x8 per thread
    const __bf16* kbase = kws  + (size_t)(b * SEQ + sr) * 64 + sc;
    const __bf16* vbase = vTws + ((size_t)b * 64 + sr) * SEQ + sc;

    bf16x8 kr[4], vr[4];
    float4 bvn[4]; int4 mkn[4];

    auto loadt = [&](int kt) {
        const __bf16* ks = kbase + (size_t)kt * 64;
        kr[0] = *(const bf16x8*)ks;
        kr[1] = *(const bf16x8*)(ks + 8);
        kr[2] = *(const bf16x8*)(ks + 16);
        kr[3] = *(const bf16x8*)(ks + 24);
        const __bf16* vs = vbase + kt;
        vr[0] = *(const bf16x8*)vs;
        vr[1] = *(const bf16x8*)(vs + 8);
        vr[2] = *(const bf16x8*)(vs + 16);
        vr[3] = *(const bf16x8*)(vs + 24);
        #pragma unroll
        for (int s2t = 0; s2t < 4; ++s2t) {
            bvn[s2t] = *(const float4*)(brow + kt + s2t * 16 + 4 * g);
            mkn[s2t] = *(const int4*)(mrow + kt + s2t * 16 + 4 * g);
        }
    };

    loadt(0);

    #pragma unroll 2
    for (int kt = 0; kt < SEQ; kt += 64) {
        *(bf16x8*)&Kl[sr * 72 + sc]      = kr[0];
        *(bf16x8*)&Kl[sr * 72 + sc + 8]  = kr[1];
        *(bf16x8*)&Kl[sr * 72 + sc + 16] = kr[2];
        *(bf16x8*)&Kl[sr * 72 + sc + 24] = kr[3];
        *(bf16x8*)&Vl[sr * 72 + sc]      = vr[0];
        *(bf16x8*)&Vl[sr * 72 + sc + 8]  = vr[1];
        *(bf16x8*)&Vl[sr * 72 + sc + 16] = vr[2];
        *(bf16x8*)&Vl[sr * 72 + sc + 24] = vr[3];
        float4 bv4[4]; int4 mk4[4];
        #pragma unroll
        for (int s2t = 0; s2t < 4; ++s2t) { bv4[s2t] = bvn[s2t]; mk4[s2t] = mkn[s2t]; }
        __syncthreads();

        if (kt + 64 < SEQ) loadt(kt + 64);

        float p[16];
        #pragma unroll
        for (int s2t = 0; s2t < 4; ++s2t) {
            const int s2 = s2t * 16;
            f32x4 acc = {};
            #pragma unroll
            for (int dt = 0; dt < 2; ++dt) {
                bf16x4 klo = *(const bf16x4*)&Kl[(s2 + lr) * 72 + dt * 32 + 4 * g];
                bf16x4 khi = *(const bf16x4*)&Kl[(s2 + lr) * 72 + dt * 32 + 16 + 4 * g];
                bf16x8 kf = __builtin_shufflevector(klo, khi, 0, 1, 2, 3, 4, 5, 6, 7);
                acc = __builtin_amdgcn_mfma_f32_16x16x32_bf16(kf, qf[dt], acc, 0, 0, 0);
            }
            p[s2t * 4 + 0] = mk4[s2t].x ? acc[0] + 0.125f * bv4[s2t].x : -1e30f;
            p[s2t * 4 + 1] = mk4[s2t].y ? acc[1] + 0.125f * bv4[s2t].y : -1e30f;
            p[s2t * 4 + 2] = mk4[s2t].z ? acc[2] + 0.125f * bv4[s2t].z : -1e30f;
            p[s2t * 4 + 3] = mk4[s2t].w ? acc[3] + 0.125f * bv4[s2t].w : -1e30f;
        }

        float tmax = p[0];
        #pragma unroll
        for (int i = 1; i < 16; ++i) tmax = fmaxf(tmax, p[i]);
        tmax = fmaxf(tmax, __shfl_xor(tmax, 16));
        tmax = fmaxf(tmax, __shfl_xor(tmax, 32));
        const float mnew  = fmaxf(m, tmax);
        const float scale = __expf(m - mnew);
        m = mnew;
        float ssum = 0.0f;
        #pragma unroll
        for (int i = 0; i < 16; ++i) { p[i] = __expf(p[i] - mnew); ssum += p[i]; }
        ssum += __shfl_xor(ssum, 16);
        ssum += __shfl_xor(ssum, 32);
        ell = ell * scale + ssum;

        float scr[4];
        #pragma unroll
        for (int rr = 0; rr < 4; ++rr) scr[rr] = __shfl(scale, 4 * g + rr);
        #pragma unroll
        for (int t = 0; t < 4; ++t)
            #pragma unroll
            for (int rr = 0; rr < 4; ++rr) O[t][rr] *= scr[rr];

        bf16x8 pf0 = { (__bf16)p[0],  (__bf16)p[1],  (__bf16)p[2],  (__bf16)p[3],
                       (__bf16)p[4],  (__bf16)p[5],  (__bf16)p[6],  (__bf16)p[7] };
        bf16x8 pf1 = { (__bf16)p[8],  (__bf16)p[9],  (__bf16)p[10], (__bf16)p[11],
                       (__bf16)p[12], (__bf16)p[13], (__bf16)p[14], (__bf16)p[15] };

        #pragma unroll
        for (int t = 0; t < 4; ++t) {
            const int dr = (t * 16 + lr) * 72;
            bf16x4 v0lo = *(const bf16x4*)&Vl[dr + 4 * g];
            bf16x4 v0hi = *(const bf16x4*)&Vl[dr + 16 + 4 * g];
            bf16x8 vf0 = __builtin_shufflevector(v0lo, v0hi, 0, 1, 2, 3, 4, 5, 6, 7);
            O[t] = __builtin_amdgcn_mfma_f32_16x16x32_bf16(pf0, vf0, O[t], 0, 0, 0);
            bf16x4 v1lo = *(const bf16x4*)&Vl[dr + 32 + 4 * g];
            bf16x4 v1hi = *(const bf16x4*)&Vl[dr + 48 + 4 * g];
            bf16x8 vf1 = __builtin_shufflevector(v1lo, v1hi, 0, 1, 2, 3, 4, 5, 6, 7);
            O[t] = __builtin_amdgcn_mfma_f32_16x16x32_bf16(pf1, vf1, O[t], 0, 0, 0);
        }
        __syncthreads();
    }

    float linv[4];
    #pragma unroll
    for (int rr = 0; rr < 4; ++rr) linv[rr] = 1.0f / __shfl(ell, 4 * g + rr);

    float* orow = out + (size_t)(b * SEQ + q0 + wv * 16) * 64;
    #pragma unroll
    for (int t = 0; t < 4; ++t)
        #pragma unroll
        for (int rr = 0; rr < 4; ++rr)
            orow[(size_t)(4 * g + rr) * 64 + t * 16 + lr] = O[t][rr] * linv[rr];
}

extern "C" void kernel_launch(void* const* d_in, const int* in_sizes, int n_in,
                              void* d_out, int out_size, void* d_ws, size_t ws_size,
                              hipStream_t stream) {
    const float* query = (const float*)d_in[0];
    const float* key_  = (const float*)d_in[1];
    const float* value = (const float*)d_in[2];
    const float* rb    = (const float*)d_in[3];
    const int*   mask  = (const int*)d_in[4];
    const float* Wq = (const float*)d_in[5];
    const float* bq = (const float*)d_in[6];
    const float* Wk = (const float*)d_in[7];
    const float* bk = (const float*)d_in[8];
    const float* Wv = (const float*)d_in[9];
    const float* bv = (const float*)d_in[10];

    __bf16* qws = (__bf16*)d_ws;                       // [16384][64]
    __bf16* kws = qws + (size_t)16384 * 64;            // [16384][64]
    __bf16* vT  = kws + (size_t)16384 * 64;            // [8][64][2048]
    __bf16* Wbf = vT  + (size_t)8 * 64 * SEQ;          // [3][64][1024] bf16

    hipLaunchKernelGGL(prep_w, dim3(192), dim3(256), 0, stream, Wq, Wk, Wv, Wbf);
    hipLaunchKernelGGL(proj_kernel, dim3(256, 3), dim3(256), 0, stream,
                       query, key_, value, Wbf, bq, bk, bv, qws, kws, vT);
    hipLaunchKernelGGL(attn_kernel, dim3(512), dim3(128), 0, stream,
                       qws, kws, vT, rb, mask, (float*)d_out);
}